// Round 3
// baseline (8813.360 us; speedup 1.0000x reference)
//
#include <hip/hip_runtime.h>
#include <math.h>

// 3-layer LSTM (H=64, T=512, B=2048, Din=16) fused persistent kernel.
// Each block owns CB=8 batch rows and runs the whole time loop for all 3
// layers, pipelined: layer l processes timestep (it - l). Weights are held in
// registers (one gate row per thread: 256 rows/layer x 3 layers = 768 threads).
// R3 fix: amdgpu_waves_per_eu(3,3) — launch_bounds(,3) was non-binding (it's a
// MINIMUM; compiler chose 6 waves/EU + spill -> 18.6 GB scratch HBM traffic).
// Pinning max=3 gives regalloc the full ~168-VGPR budget for the weight rows.

#define TSTEPS 512
#define HID    64
#define G4     256   // 4*HID
#define DIN0   16
#define CB     8     // batch rows per block
#define NTHREADS 768
#define BATCH  2048

__device__ __forceinline__ float sigm(float z) {
    return 1.0f / (1.0f + __expf(-z));
}
__device__ __forceinline__ float tanh_fast(float z) {
    z = fminf(15.0f, fmaxf(-15.0f, z));
    const float e = __expf(2.0f * z);
    return (e - 1.0f) / (e + 1.0f);
}

__global__ void __launch_bounds__(NTHREADS)
__attribute__((amdgpu_waves_per_eu(3, 3)))
lstm3_fused(
    const float* __restrict__ x,      // [B, T, 16]
    const float* __restrict__ Wih0,   // [256,16]
    const float* __restrict__ Whh0,   // [256,64]
    const float* __restrict__ bih0,   // [256]
    const float* __restrict__ bhh0,   // [256]
    const float* __restrict__ Wih1,   // [256,64]
    const float* __restrict__ Whh1,   // [256,64]
    const float* __restrict__ bih1,
    const float* __restrict__ bhh1,
    const float* __restrict__ Wih2,   // [256,64]
    const float* __restrict__ Whh2,   // [256,64]
    const float* __restrict__ bih2,
    const float* __restrict__ bhh2,
    const float* __restrict__ Wout,   // [7,64]
    const float* __restrict__ bout,   // [7]
    float* __restrict__ out)          // [B,7]
{
    __shared__ __attribute__((aligned(16))) float xs[2][CB][DIN0];
    __shared__ __attribute__((aligned(16))) float h0b[2][CB][HID];
    __shared__ __attribute__((aligned(16))) float h1b[2][CB][HID];
    __shared__ __attribute__((aligned(16))) float h2b[2][CB][HID];
    __shared__ __attribute__((aligned(16))) float gates[3][CB][G4];

    const int tid = threadIdx.x;
    const int grp = tid >> 8;     // layer group 0..2
    const int r   = tid & 255;    // gate row within layer
    const int b0  = blockIdx.x * CB;

    // ---- load this thread's gate-row weights into registers (float4,
    //      compile-time indices only -> SROA to VGPRs) ----
    float4 wih4[HID / 4];
    float4 whh4[HID / 4];
    float bias;
    if (grp == 0) {
        const float4* wi = (const float4*)(Wih0 + r * DIN0);
        #pragma unroll
        for (int k = 0; k < DIN0 / 4; ++k) wih4[k] = wi[k];
        #pragma unroll
        for (int k = DIN0 / 4; k < HID / 4; ++k)
            wih4[k] = make_float4(0.f, 0.f, 0.f, 0.f);
        const float4* wh = (const float4*)(Whh0 + r * HID);
        #pragma unroll
        for (int k = 0; k < HID / 4; ++k) whh4[k] = wh[k];
        bias = bih0[r] + bhh0[r];
    } else if (grp == 1) {
        const float4* wi = (const float4*)(Wih1 + r * HID);
        const float4* wh = (const float4*)(Whh1 + r * HID);
        #pragma unroll
        for (int k = 0; k < HID / 4; ++k) { wih4[k] = wi[k]; whh4[k] = wh[k]; }
        bias = bih1[r] + bhh1[r];
    } else {
        const float4* wi = (const float4*)(Wih2 + r * HID);
        const float4* wh = (const float4*)(Whh2 + r * HID);
        #pragma unroll
        for (int k = 0; k < HID / 4; ++k) { wih4[k] = wi[k]; whh4[k] = wh[k]; }
        bias = bih2[r] + bhh2[r];
    }

    // ---- zero h double-buffers (both slots), stage x[t=0] ----
    for (int i = tid; i < 2 * CB * HID; i += NTHREADS) {
        (&h0b[0][0][0])[i] = 0.0f;
        (&h1b[0][0][0])[i] = 0.0f;
        (&h2b[0][0][0])[i] = 0.0f;
    }
    if (tid < 128) {
        xs[0][tid >> 4][tid & 15] =
            x[(b0 + (tid >> 4)) * (TSTEPS * DIN0) + (tid & 15)];
    }

    float cst0 = 0.0f, cst1 = 0.0f;   // c state: 2 (batch,unit) cells per thread

    __syncthreads();

    for (int it = 0; it < TSTEPS + 2; ++it) {
        const int t = it - grp;                  // this group's timestep
        const bool act = (t >= 0) && (t < TSTEPS);
        const int ps = (it + 1) & 1;             // previous h slot = (it-1)&1

        // ================= Phase A: gate pre-activations =================
        if (act) {
            float acc[CB];
            #pragma unroll
            for (int b = 0; b < CB; ++b) acc[b] = bias;

            if (grp == 0) {
                const float* src = &xs[t & 1][0][0];
                #pragma unroll
                for (int k4 = 0; k4 < DIN0 / 4; ++k4) {
                    #pragma unroll
                    for (int b = 0; b < CB; ++b) {
                        const float4 a = *(const float4*)(src + b * DIN0 + k4 * 4);
                        acc[b] = fmaf(a.x, wih4[k4].x, acc[b]);
                        acc[b] = fmaf(a.y, wih4[k4].y, acc[b]);
                        acc[b] = fmaf(a.z, wih4[k4].z, acc[b]);
                        acc[b] = fmaf(a.w, wih4[k4].w, acc[b]);
                    }
                }
            } else {
                const float* src = (grp == 1) ? &h0b[ps][0][0] : &h1b[ps][0][0];
                #pragma unroll
                for (int k4 = 0; k4 < HID / 4; ++k4) {
                    #pragma unroll
                    for (int b = 0; b < CB; ++b) {
                        const float4 a = *(const float4*)(src + b * HID + k4 * 4);
                        acc[b] = fmaf(a.x, wih4[k4].x, acc[b]);
                        acc[b] = fmaf(a.y, wih4[k4].y, acc[b]);
                        acc[b] = fmaf(a.z, wih4[k4].z, acc[b]);
                        acc[b] = fmaf(a.w, wih4[k4].w, acc[b]);
                    }
                }
            }
            {
                const float* hs = (grp == 0) ? &h0b[ps][0][0]
                                : (grp == 1) ? &h1b[ps][0][0]
                                             : &h2b[ps][0][0];
                #pragma unroll
                for (int k4 = 0; k4 < HID / 4; ++k4) {
                    #pragma unroll
                    for (int b = 0; b < CB; ++b) {
                        const float4 a = *(const float4*)(hs + b * HID + k4 * 4);
                        acc[b] = fmaf(a.x, whh4[k4].x, acc[b]);
                        acc[b] = fmaf(a.y, whh4[k4].y, acc[b]);
                        acc[b] = fmaf(a.z, whh4[k4].z, acc[b]);
                        acc[b] = fmaf(a.w, whh4[k4].w, acc[b]);
                    }
                }
            }
            float* gdst = &gates[grp][0][0];
            #pragma unroll
            for (int b = 0; b < CB; ++b) gdst[b * G4 + r] = acc[b];
        }
        __syncthreads();

        // ================= Phase B: elementwise update ===================
        if (act) {
            const int u  = r & 63;
            const int bb = r >> 6;     // handles batch rows bb and bb+4
            float* hdst = (grp == 0) ? &h0b[it & 1][0][0]
                        : (grp == 1) ? &h1b[it & 1][0][0]
                                     : &h2b[it & 1][0][0];
            const float* gsrc = &gates[grp][0][0];
            {
                const int b = bb;
                const float gi = gsrc[b * G4 + u];
                const float gf = gsrc[b * G4 + 64 + u];
                const float gg = gsrc[b * G4 + 128 + u];
                const float go = gsrc[b * G4 + 192 + u];
                const float c  = sigm(gf) * cst0 + sigm(gi) * tanh_fast(gg);
                cst0 = c;
                hdst[b * HID + u] = sigm(go) * tanh_fast(c);
            }
            {
                const int b = bb + 4;
                const float gi = gsrc[b * G4 + u];
                const float gf = gsrc[b * G4 + 64 + u];
                const float gg = gsrc[b * G4 + 128 + u];
                const float go = gsrc[b * G4 + 192 + u];
                const float c  = sigm(gf) * cst1 + sigm(gi) * tanh_fast(gg);
                cst1 = c;
                hdst[b * HID + u] = sigm(go) * tanh_fast(c);
            }
        }
        // stage next x tile (group 0's next timestep), hidden under phase B
        if (grp == 0 && r < 128 && (it + 1) < TSTEPS) {
            xs[(it + 1) & 1][r >> 4][r & 15] =
                x[(b0 + (r >> 4)) * (TSTEPS * DIN0) + (it + 1) * DIN0 + (r & 15)];
        }
        __syncthreads();
    }

    // ================= head: out = h2[T-1] @ Wout.T + bout ==============
    if (grp == 2 && r < 7 * CB) {
        const int b = r / 7;
        const int o = r % 7;
        float a2 = bout[o];
        #pragma unroll
        for (int k = 0; k < HID; ++k)
            a2 = fmaf(h2b[(TSTEPS + 1) & 1][b][k], Wout[o * HID + k], a2);
        out[(b0 + b) * 7 + o] = a2;
    }
}

extern "C" void kernel_launch(void* const* d_in, const int* in_sizes, int n_in,
                              void* d_out, int out_size, void* d_ws, size_t ws_size,
                              hipStream_t stream) {
    const float* x    = (const float*)d_in[0];
    const float* Wih0 = (const float*)d_in[1];
    const float* Whh0 = (const float*)d_in[2];
    const float* bih0 = (const float*)d_in[3];
    const float* bhh0 = (const float*)d_in[4];
    const float* Wih1 = (const float*)d_in[5];
    const float* Whh1 = (const float*)d_in[6];
    const float* bih1 = (const float*)d_in[7];
    const float* bhh1 = (const float*)d_in[8];
    const float* Wih2 = (const float*)d_in[9];
    const float* Whh2 = (const float*)d_in[10];
    const float* bih2 = (const float*)d_in[11];
    const float* bhh2 = (const float*)d_in[12];
    const float* Wout = (const float*)d_in[13];
    const float* bout = (const float*)d_in[14];
    float* out = (float*)d_out;

    lstm3_fused<<<dim3(BATCH / CB), dim3(NTHREADS), 0, stream>>>(
        x, Wih0, Whh0, bih0, bhh0,
        Wih1, Whh1, bih1, bhh1,
        Wih2, Whh2, bih2, bhh2,
        Wout, bout, out);
}

// Round 4
// 6641.029 us; speedup vs baseline: 1.3271x; 1.3271x over previous
//
#include <hip/hip_runtime.h>
#include <math.h>

// 3-layer LSTM (H=64, T=512, B=2048, Din=16) fused persistent kernel, R4.
// Structure: 256 blocks x 768 threads; block owns CB=8 batch rows; 3 layer
// groups of 256 threads pipelined in time (group g computes timestep it-g).
// R4 rewrite of Phase A:
//  - weights in ext_vector_type(16) NAMED vectors (SSA by construction; the
//    float4-array version was never promoted -> lived in scratch -> 19 GB/iter
//    of HBM spill traffic, 8.8 ms).
//  - h/x broadcast via v_readlane from lane-resident registers (8 ds_read_b32
//    per operand set) instead of 256 broadcast ds_read_b128 per thread/iter.

#define TSTEPS 512
#define HID    64
#define G4     256   // 4*HID
#define DIN0   16
#define CB     8     // batch rows per block
#define NTHREADS 768
#define BATCH  2048

typedef float f16v __attribute__((ext_vector_type(16)));

__device__ __forceinline__ float sigm(float z) {
    return 1.0f / (1.0f + __expf(-z));
}
__device__ __forceinline__ float tanh_fast(float z) {
    z = fminf(15.0f, fmaxf(-15.0f, z));
    const float e = __expf(2.0f * z);
    return (e - 1.0f) / (e + 1.0f);
}
// wave-uniform broadcast of lane k's value (v_readlane -> SGPR operand to FMA)
__device__ __forceinline__ float bcast(float v, int k) {
    return __int_as_float(__builtin_amdgcn_readlane(__float_as_int(v), k));
}

// acc_b += h[b][KB+k_] * W[k_]  for b in 0..7, k_ in 0..15
#define DOT16(W, KB) do {                                          \
    _Pragma("unroll")                                              \
    for (int k_ = 0; k_ < 16; ++k_) {                              \
        const float w_ = (W)[k_];                                  \
        acc0 = fmaf(bcast(v0, (KB) + k_), w_, acc0);               \
        acc1 = fmaf(bcast(v1, (KB) + k_), w_, acc1);               \
        acc2 = fmaf(bcast(v2, (KB) + k_), w_, acc2);               \
        acc3 = fmaf(bcast(v3, (KB) + k_), w_, acc3);               \
        acc4 = fmaf(bcast(v4, (KB) + k_), w_, acc4);               \
        acc5 = fmaf(bcast(v5, (KB) + k_), w_, acc5);               \
        acc6 = fmaf(bcast(v6, (KB) + k_), w_, acc6);               \
        acc7 = fmaf(bcast(v7, (KB) + k_), w_, acc7);               \
    }                                                              \
} while (0)

#define LOADV(SRC, STRIDE, IDX)                                    \
    v0 = (SRC)[0 * (STRIDE) + (IDX)];                              \
    v1 = (SRC)[1 * (STRIDE) + (IDX)];                              \
    v2 = (SRC)[2 * (STRIDE) + (IDX)];                              \
    v3 = (SRC)[3 * (STRIDE) + (IDX)];                              \
    v4 = (SRC)[4 * (STRIDE) + (IDX)];                              \
    v5 = (SRC)[5 * (STRIDE) + (IDX)];                              \
    v6 = (SRC)[6 * (STRIDE) + (IDX)];                              \
    v7 = (SRC)[7 * (STRIDE) + (IDX)];

__global__
__attribute__((amdgpu_flat_work_group_size(NTHREADS, NTHREADS),
               amdgpu_waves_per_eu(3, 3)))
void lstm3_fused(
    const float* __restrict__ x,      // [B, T, 16]
    const float* __restrict__ Wih0,   // [256,16]
    const float* __restrict__ Whh0,   // [256,64]
    const float* __restrict__ bih0,   // [256]
    const float* __restrict__ bhh0,   // [256]
    const float* __restrict__ Wih1,   // [256,64]
    const float* __restrict__ Whh1,   // [256,64]
    const float* __restrict__ bih1,
    const float* __restrict__ bhh1,
    const float* __restrict__ Wih2,   // [256,64]
    const float* __restrict__ Whh2,   // [256,64]
    const float* __restrict__ bih2,
    const float* __restrict__ bhh2,
    const float* __restrict__ Wout,   // [7,64]
    const float* __restrict__ bout,   // [7]
    float* __restrict__ out)          // [B,7]
{
    __shared__ __attribute__((aligned(16))) float xs[2][CB][DIN0];
    __shared__ __attribute__((aligned(16))) float h0b[2][CB][HID];
    __shared__ __attribute__((aligned(16))) float h1b[2][CB][HID];
    __shared__ __attribute__((aligned(16))) float h2b[2][CB][HID];
    __shared__ __attribute__((aligned(16))) float gates[3][CB][G4];

    const int tid  = threadIdx.x;
    const int grp  = tid >> 8;     // layer group 0..2
    const int r    = tid & 255;    // gate row within layer
    const int lane = tid & 63;
    const int b0   = blockIdx.x * CB;

    // ---- weights as SSA vector values (no alloca -> no scratch) ----
    f16v WH0, WH1, WH2, WH3;   // whh row: 64 floats
    f16v WI0, WI1, WI2, WI3;   // wih row: 64 floats (grp0 uses WI0 only)
    float bias;
    {
        const float* whhp = (grp == 0) ? Whh0 : (grp == 1) ? Whh1 : Whh2;
        const f16v* wp = (const f16v*)(whhp + r * HID);
        WH0 = wp[0]; WH1 = wp[1]; WH2 = wp[2]; WH3 = wp[3];
    }
    if (grp == 0) {
        WI0 = *(const f16v*)(Wih0 + r * DIN0);
        bias = bih0[r] + bhh0[r];
    } else if (grp == 1) {
        const f16v* wp = (const f16v*)(Wih1 + r * HID);
        WI0 = wp[0]; WI1 = wp[1]; WI2 = wp[2]; WI3 = wp[3];
        bias = bih1[r] + bhh1[r];
    } else {
        const f16v* wp = (const f16v*)(Wih2 + r * HID);
        WI0 = wp[0]; WI1 = wp[1]; WI2 = wp[2]; WI3 = wp[3];
        bias = bih2[r] + bhh2[r];
    }

    // ---- zero h double-buffers (both slots), stage x[t=0] ----
    for (int i = tid; i < 2 * CB * HID; i += NTHREADS) {
        (&h0b[0][0][0])[i] = 0.0f;
        (&h1b[0][0][0])[i] = 0.0f;
        (&h2b[0][0][0])[i] = 0.0f;
    }
    if (tid < 128) {
        xs[0][tid >> 4][tid & 15] =
            x[(b0 + (tid >> 4)) * (TSTEPS * DIN0) + (tid & 15)];
    }

    float cst0 = 0.0f, cst1 = 0.0f;   // c state: 2 (batch,unit) cells/thread

    __syncthreads();

    for (int it = 0; it < TSTEPS + 2; ++it) {
        const int t = it - grp;                  // this group's timestep
        const bool act = (t >= 0) && (t < TSTEPS);
        const int ps = (it + 1) & 1;             // previous h slot

        // ================= Phase A: gate pre-activations =================
        if (act) {
            float acc0 = bias, acc1 = bias, acc2 = bias, acc3 = bias;
            float acc4 = bias, acc5 = bias, acc6 = bias, acc7 = bias;
            float v0, v1, v2, v3, v4, v5, v6, v7;

            // ---- input-side GEMV (x for grp0, previous layer's h else) ----
            if (grp == 0) {
                const float* src = &xs[t & 1][0][0];
                LOADV(src, DIN0, lane & 15)
                DOT16(WI0, 0);
            } else {
                const float* src = (grp == 1) ? &h0b[ps][0][0]
                                              : &h1b[ps][0][0];
                LOADV(src, HID, lane)
                DOT16(WI0, 0);
                DOT16(WI1, 16);
                DOT16(WI2, 32);
                DOT16(WI3, 48);
            }
            // ---- recurrent-side GEMV (own h, previous step) ----
            {
                const float* hs = (grp == 0) ? &h0b[ps][0][0]
                                : (grp == 1) ? &h1b[ps][0][0]
                                             : &h2b[ps][0][0];
                LOADV(hs, HID, lane)
                DOT16(WH0, 0);
                DOT16(WH1, 16);
                DOT16(WH2, 32);
                DOT16(WH3, 48);
            }
            float* gd = &gates[grp][0][0];
            gd[0 * G4 + r] = acc0;  gd[1 * G4 + r] = acc1;
            gd[2 * G4 + r] = acc2;  gd[3 * G4 + r] = acc3;
            gd[4 * G4 + r] = acc4;  gd[5 * G4 + r] = acc5;
            gd[6 * G4 + r] = acc6;  gd[7 * G4 + r] = acc7;
        }
        __syncthreads();

        // ================= Phase B: elementwise update ===================
        if (act) {
            const int u  = r & 63;
            const int bb = r >> 6;     // handles batch rows bb and bb+4
            float* hdst = (grp == 0) ? &h0b[it & 1][0][0]
                        : (grp == 1) ? &h1b[it & 1][0][0]
                                     : &h2b[it & 1][0][0];
            const float* gsrc = &gates[grp][0][0];
            {
                const int b = bb;
                const float gi = gsrc[b * G4 + u];
                const float gf = gsrc[b * G4 + 64 + u];
                const float gg = gsrc[b * G4 + 128 + u];
                const float go = gsrc[b * G4 + 192 + u];
                const float c  = sigm(gf) * cst0 + sigm(gi) * tanh_fast(gg);
                cst0 = c;
                hdst[b * HID + u] = sigm(go) * tanh_fast(c);
            }
            {
                const int b = bb + 4;
                const float gi = gsrc[b * G4 + u];
                const float gf = gsrc[b * G4 + 64 + u];
                const float gg = gsrc[b * G4 + 128 + u];
                const float go = gsrc[b * G4 + 192 + u];
                const float c  = sigm(gf) * cst1 + sigm(gi) * tanh_fast(gg);
                cst1 = c;
                hdst[b * HID + u] = sigm(go) * tanh_fast(c);
            }
        }
        // stage next x tile (group 0's next timestep), hidden under phase B
        if (grp == 0 && r < 128 && (it + 1) < TSTEPS) {
            xs[(it + 1) & 1][r >> 4][r & 15] =
                x[(b0 + (r >> 4)) * (TSTEPS * DIN0) + (it + 1) * DIN0 + (r & 15)];
        }
        __syncthreads();
    }

    // ================= head: out = h2[T-1] @ Wout.T + bout ==============
    if (grp == 2 && r < 7 * CB) {
        const int b = r / 7;
        const int o = r % 7;
        float a2 = bout[o];
        #pragma unroll
        for (int k = 0; k < HID; ++k)
            a2 = fmaf(h2b[(TSTEPS + 1) & 1][b][k], Wout[o * HID + k], a2);
        out[(b0 + b) * 7 + o] = a2;
    }
}

extern "C" void kernel_launch(void* const* d_in, const int* in_sizes, int n_in,
                              void* d_out, int out_size, void* d_ws, size_t ws_size,
                              hipStream_t stream) {
    const float* x    = (const float*)d_in[0];
    const float* Wih0 = (const float*)d_in[1];
    const float* Whh0 = (const float*)d_in[2];
    const float* bih0 = (const float*)d_in[3];
    const float* bhh0 = (const float*)d_in[4];
    const float* Wih1 = (const float*)d_in[5];
    const float* Whh1 = (const float*)d_in[6];
    const float* bih1 = (const float*)d_in[7];
    const float* bhh1 = (const float*)d_in[8];
    const float* Wih2 = (const float*)d_in[9];
    const float* Whh2 = (const float*)d_in[10];
    const float* bih2 = (const float*)d_in[11];
    const float* bhh2 = (const float*)d_in[12];
    const float* Wout = (const float*)d_in[13];
    const float* bout = (const float*)d_in[14];
    float* out = (float*)d_out;

    lstm3_fused<<<dim3(BATCH / CB), dim3(NTHREADS), 0, stream>>>(
        x, Wih0, Whh0, bih0, bhh0,
        Wih1, Whh1, bih1, bhh1,
        Wih2, Whh2, bih2, bhh2,
        Wout, bout, out);
}